// Round 5
// baseline (1084.646 us; speedup 1.0000x reference)
//
#include <hip/hip_runtime.h>
#include <hip/hip_bf16.h>
#include <stdint.h>

#define B_ 16
#define S_ 2048
#define H_ 1024
static constexpr float NEG_INF_F = -10000000.0f;
static constexpr float SCALE_F   = 0.03125f;   // 1/sqrt(1024)

#define BM 128
#define BN 128
#define BK 32

typedef __attribute__((ext_vector_type(4))) float  f32x4;
typedef __attribute__((ext_vector_type(8))) short  bf16x8;
typedef __attribute__((ext_vector_type(4))) short  s16x4;

__device__ __forceinline__ short f2bf(float f) {
  uint32_t u = __float_as_uint(f);
  u = (u + 0x7FFFu + ((u >> 16) & 1u)) >> 16;   // RNE bf16
  return (short)u;
}

__device__ __forceinline__ void gload16(const void* g, void* l) {
  __builtin_amdgcn_global_load_lds(
      (const __attribute__((address_space(1))) unsigned int*)g,
      (__attribute__((address_space(3))) unsigned int*)l, 16, 0, 0);
}

// Stage a 128x32 bf16 tile into linear LDS [128][32] via global_load_lds w=16.
// Wave w covers rows [w*32,+32) in 2 issues; lane l -> row +(l>>2), col (l&3)*8.
__device__ __forceinline__ void stage_gl(const short* __restrict__ src, int ld,
                                         short* __restrict__ lds) {
  const int w = threadIdx.x >> 6;
  const int l = threadIdx.x & 63;
  #pragma unroll
  for (int i = 0; i < 2; ++i) {
    const int rbase = w * 32 + i * 16;
    const int r = rbase + (l >> 2);
    gload16(src + (size_t)r * ld + ((l & 3) << 3), &lds[rbase * 32]);
  }
}

// Pipelined 128x128xK bf16 GEMM core: C[m][n] = sum_k A[m][k]*B[n][k].
// 3 LDS buffers, 2-ahead prefetch, counted vmcnt across raw barriers (T3/T4),
// setprio around MFMA (T5).
// MODE 0: +bias, out bf16 row-major   MODE 1: +bias, out bf16 transposed (V^T)
// MODE 2: out f32 = acc*scale + causal mask   MODE 3: out f32 (context)
template<int MODE>
__device__ __forceinline__ void gemm_core(
    const short* __restrict__ A, const short* __restrict__ Bm,
    const float* __restrict__ bias, void* __restrict__ Cp,
    int K, int lda, int ldb, int ldc, int z, long long strC,
    int row0, int col0, int bx, short* shA, short* shB) {
  const int lane = threadIdx.x & 63;
  const int wid  = threadIdx.x >> 6;
  const int wm = (wid >> 1) * 64;
  const int wn = (wid & 1) * 64;
  const int lr = lane & 15;
  const int lk = (lane >> 4) << 3;

  int kmain = K;
  if constexpr (MODE == 3) {
    int km = (bx + 1) * BM;               // rows q<row0+BM: attn nonzero only k<q
    kmain = km < K ? km : K;
  }
  const int ntm = kmain / BK;
  const int nt  = ntm + ((MODE == 3 && kmain < K) ? (BM / BK) : 0);
  auto kt_of = [&](int i) -> int {
    if (i < ntm) return i * BK;
    return K - BM + (i - ntm) * BK;       // dense attn column 2047 segment
  };
  auto stage = [&](int buf, int kt) {     // 4 gload16 per thread
    stage_gl(A  + (size_t)row0 * lda + kt, lda, shA + buf * (BM * 32));
    stage_gl(Bm + (size_t)col0 * ldb + kt, ldb, shB + buf * (BN * 32));
  };

  f32x4 acc[4][4] = {};

  stage(0, kt_of(0));                     // nt >= 8 in all modes
  stage(1, kt_of(1));
  int cur = 0;
  for (int i = 0; i < nt; ++i) {
    // own tile-i loads retired (oldest 4); tile-(i+1)'s 4 may stay in flight
    if (i + 1 < nt) asm volatile("s_waitcnt vmcnt(4)" ::: "memory");
    else            asm volatile("s_waitcnt vmcnt(0)" ::: "memory");
    __builtin_amdgcn_s_barrier();         // all waves' tile-i portions in LDS
    __builtin_amdgcn_sched_barrier(0);
    if (i + 2 < nt) stage(cur == 0 ? 2 : cur - 1, kt_of(i + 2));

    const short* sA = shA + cur * (BM * 32);
    const short* sB = shB + cur * (BN * 32);
    bf16x8 af[4], bfr[4];
    #pragma unroll
    for (int m = 0; m < 4; ++m) {
      af[m]  = *(const bf16x8*)&sA[(wm + m * 16 + lr) * 32 + lk];
      bfr[m] = *(const bf16x8*)&sB[(wn + m * 16 + lr) * 32 + lk];
    }
    __builtin_amdgcn_s_setprio(1);
    #pragma unroll
    for (int m = 0; m < 4; ++m)
      #pragma unroll
      for (int n = 0; n < 4; ++n)
        acc[m][n] = __builtin_amdgcn_mfma_f32_16x16x32_bf16(af[m], bfr[n], acc[m][n], 0, 0, 0);
    __builtin_amdgcn_s_setprio(0);
    cur = (cur == 2) ? 0 : cur + 1;
  }

  // C/D layout: col = lane&15, row = (lane>>4)*4 + reg
  #pragma unroll
  for (int i = 0; i < 4; ++i) {
    #pragma unroll
    for (int j = 0; j < 4; ++j) {
      const int mb = row0 + wm + i * 16 + ((lane >> 4) << 2);
      const int n  = col0 + wn + j * 16 + lr;
      f32x4 a = acc[i][j];
      if constexpr (MODE == 0) {
        short* out = (short*)Cp;
        const float bv = bias[n];
        #pragma unroll
        for (int r = 0; r < 4; ++r)
          out[(size_t)(mb + r) * ldc + n] = f2bf(a[r] + bv);
      } else if constexpr (MODE == 1) {
        const float bv = bias[n];
        const int bb = mb >> 11;          // batch (S_=2048)
        const int ss = mb & (S_ - 1);
        s16x4 pk;
        #pragma unroll
        for (int r = 0; r < 4; ++r) pk[r] = f2bf(a[r] + bv);
        *(s16x4*)((short*)Cp + ((size_t)bb * H_ + n) * S_ + ss) = pk;
      } else if constexpr (MODE == 2) {
        float* out = (float*)Cp + (size_t)z * strC;
        #pragma unroll
        for (int r = 0; r < 4; ++r) {
          const int m = mb + r;
          out[(size_t)m * ldc + n] = a[r] * SCALE_F + (n >= m ? NEG_INF_F : 0.0f);
        }
      } else {
        float* out = (float*)Cp + (size_t)z * strC;
        #pragma unroll
        for (int r = 0; r < 4; ++r)
          out[(size_t)(mb + r) * ldc + n] = a[r];
      }
    }
  }
}

struct ProjArgs {
  const short *xq, *xk, *xv, *wq, *wk, *wv;
  const float *bq, *bk, *bv;
  short *oq, *ok, *ov;
};

// All three projections in one launch; grid (8, 256, 3), z selects Q/K/V.
__launch_bounds__(256)
__global__ void proj3(ProjArgs p) {
  __shared__ short shA[3 * BM * 32];
  __shared__ short shB[3 * BN * 32];
  const int z    = blockIdx.z;
  const int row0 = blockIdx.y * BM;
  const int col0 = blockIdx.x * BN;
  if (z == 0)
    gemm_core<0>(p.xq, p.wq, p.bq, p.oq, H_, H_, H_, H_, 0, 0LL, row0, col0, blockIdx.x, shA, shB);
  else if (z == 1)
    gemm_core<0>(p.xk, p.wk, p.bk, p.ok, H_, H_, H_, H_, 0, 0LL, row0, col0, blockIdx.x, shA, shB);
  else
    gemm_core<1>(p.xv, p.wv, p.bv, p.ov, H_, H_, H_, 0, 0, 0LL, row0, col0, blockIdx.x, shA, shB);
}

// Scores (+scale, +causal mask); triangular tile skip except last tile-column.
__launch_bounds__(256)
__global__ void scores_k(const short* __restrict__ Qb, const short* __restrict__ Kb,
                         float* __restrict__ attn) {
  if (blockIdx.y > blockIdx.x && blockIdx.y != gridDim.y - 1) return;
  __shared__ short shA[3 * BM * 32];
  __shared__ short shB[3 * BN * 32];
  const size_t zo = (size_t)blockIdx.z * S_ * H_;
  gemm_core<2>(Qb + zo, Kb + zo, nullptr, attn, H_, H_, H_, S_, blockIdx.z,
               (long long)S_ * S_, blockIdx.x * BM, blockIdx.y * BN, blockIdx.x, shA, shB);
}

// Context = attn_b @ V^T; triangular K-loop (+ last k-tile).
__launch_bounds__(256)
__global__ void ctx_k(const short* __restrict__ attn_b, const short* __restrict__ Vt,
                      float* __restrict__ ctx) {
  __shared__ short shA[3 * BM * 32];
  __shared__ short shB[3 * BN * 32];
  gemm_core<3>(attn_b + (size_t)blockIdx.z * S_ * S_, Vt + (size_t)blockIdx.z * H_ * S_,
               nullptr, ctx, S_, S_, S_, H_, blockIdx.z, (long long)S_ * H_,
               blockIdx.x * BM, blockIdx.y * BN, blockIdx.x, shA, shB);
}

// All six f32->bf16 conversions in one launch. grid (2048, 4).
__launch_bounds__(256)
__global__ void cvt6(const float* __restrict__ q, const float* __restrict__ k,
                     const float* __restrict__ v, const float* __restrict__ wq,
                     const float* __restrict__ wk, const float* __restrict__ wv,
                     short* __restrict__ xq, short* __restrict__ xk,
                     short* __restrict__ xv, short* __restrict__ wqb,
                     short* __restrict__ wkb, short* __restrict__ wvb) {
  const int y = blockIdx.y;
  const int stride = gridDim.x * 256;
  if (y < 3) {
    const float* s = (y == 0) ? q : (y == 1) ? k : v;
    short* d       = (y == 0) ? xq : (y == 1) ? xk : xv;
    const int n4 = (B_ * S_ * H_) / 4;
    for (int i = blockIdx.x * 256 + threadIdx.x; i < n4; i += stride) {
      f32x4 x = ((const f32x4*)s)[i];
      s16x4 o;
      #pragma unroll
      for (int j = 0; j < 4; ++j) o[j] = f2bf(x[j]);
      ((s16x4*)d)[i] = o;
    }
  } else {
    const int w4 = (H_ * H_) / 4;          // 2^18
    for (int i = blockIdx.x * 256 + threadIdx.x; i < 3 * w4; i += stride) {
      const int wsel = i >> 18;
      const int j = i & (w4 - 1);
      const float* s = (wsel == 0) ? wq : (wsel == 1) ? wk : wv;
      short* d       = (wsel == 0) ? wqb : (wsel == 1) ? wkb : wvb;
      f32x4 x = ((const f32x4*)s)[j];
      s16x4 o;
      #pragma unroll
      for (int jj = 0; jj < 4; ++jj) o[jj] = f2bf(x[jj]);
      ((s16x4*)d)[j] = o;
    }
  }
}

// Column softmax (over q axis) in place on attn (B,S,S) f32; also writes a bf16
// copy for the context GEMM. Rows q<=k are exact zeros (written, not computed).
// Block: 256 thr = 8 col-groups(x4 cols, float4) x 32 q-strides. Grid (S/32, B).
__launch_bounds__(256)
__global__ void softmax_col(float* __restrict__ attn, short* __restrict__ attn_b) {
  const int b  = blockIdx.y;
  const int t  = threadIdx.x;
  const int cg = t & 7;
  const int qo = t >> 3;                  // 0..31
  const int k0 = blockIdx.x * 32 + cg * 4;
  float* base = attn + (size_t)b * S_ * S_;
  short* bb   = attn_b + (size_t)b * S_ * S_;
  const bool full = (k0 == S_ - 4);       // group holding the all-masked col S-1

  int qstart;
  if (full) qstart = qo;
  else { const int s0 = k0 + 1; qstart = s0 + ((qo - s0) & 31); }

  f32x4 m4, s4;
  #pragma unroll
  for (int i = 0; i < 4; ++i) { m4[i] = -3.0e38f; s4[i] = 0.0f; }

  for (int q = qstart; q < S_; q += 32) {
    f32x4 x = *(const f32x4*)&base[(size_t)q * S_ + k0];
    #pragma unroll
    for (int i = 0; i < 4; ++i) {
      float mn = fmaxf(m4[i], x[i]);
      s4[i] = s4[i] * __expf(m4[i] - mn) + __expf(x[i] - mn);
      m4[i] = mn;
    }
  }

  __shared__ f32x4 smx[32][8];
  __shared__ f32x4 ssx[32][8];
  smx[qo][cg] = m4;
  ssx[qo][cg] = s4;
  __syncthreads();

  f32x4 M4, Sm;
  #pragma unroll
  for (int i = 0; i < 4; ++i) { M4[i] = -3.0e38f; Sm[i] = 0.0f; }
  for (int j = 0; j < 32; ++j) {
    f32x4 mm = smx[j][cg];
    #pragma unroll
    for (int i = 0; i < 4; ++i) M4[i] = fmaxf(M4[i], mm[i]);
  }
  for (int j = 0; j < 32; ++j) {
    f32x4 mm = smx[j][cg], ssv = ssx[j][cg];
    #pragma unroll
    for (int i = 0; i < 4; ++i) Sm[i] += ssv[i] * __expf(mm[i] - M4[i]);
  }
  f32x4 inv;
  #pragma unroll
  for (int i = 0; i < 4; ++i) inv[i] = 1.0f / Sm[i];

  for (int q = qo; q < S_; q += 32) {
    const size_t off = (size_t)q * S_ + k0;
    if (full || q > k0) {
      f32x4 x = *(const f32x4*)&base[off];
      f32x4 r;
      s16x4 rb;
      #pragma unroll
      for (int i = 0; i < 4; ++i) { r[i] = __expf(x[i] - M4[i]) * inv[i]; rb[i] = f2bf(r[i]); }
      *(f32x4*)&base[off] = r;
      *(s16x4*)&bb[off]   = rb;
    } else {
      f32x4 zr;
      s16x4 zb;
      #pragma unroll
      for (int i = 0; i < 4; ++i) { zr[i] = 0.0f; zb[i] = 0; }
      *(f32x4*)&base[off] = zr;
      *(s16x4*)&bb[off]   = zb;
    }
  }
}

extern "C" void kernel_launch(void* const* d_in, const int* in_sizes, int n_in,
                              void* d_out, int out_size, void* d_ws, size_t ws_size,
                              hipStream_t stream) {
  const float* queries = (const float*)d_in[0];
  const float* keys    = (const float*)d_in[1];
  const float* values  = (const float*)d_in[2];
  const float* Wq = (const float*)d_in[3];
  const float* bq = (const float*)d_in[4];
  const float* Wk = (const float*)d_in[5];
  const float* bk = (const float*)d_in[6];
  const float* Wv = (const float*)d_in[7];
  const float* bv = (const float*)d_in[8];

  float* ctx  = (float*)d_out;                       // (B,S,H) f32
  float* attn = ctx + (size_t)B_ * S_ * H_;          // (B,S,S) f32

  short* Qb = (short*)d_ws;                          // (B,S,H) bf16
  short* Kb = Qb + (size_t)B_ * S_ * H_;
  short* Vt = Kb + (size_t)B_ * S_ * H_;             // (B,H,S) bf16
  short* attn_b = Qb;                                // (B,S,S) bf16 reuses Qb+Kb
                                                     // (dead after scores GEMM)

  // bf16 input/weight scratch inside d_out regions written later:
  short* Wqb = (short*)ctx;                          // 3x (H,H) bf16 in ctx region
  short* Wkb = Wqb + (size_t)H_ * H_;
  short* Wvb = Wkb + (size_t)H_ * H_;
  short* Xq = (short*)attn;                          // 3x (B,S,H) bf16 in attn region
  short* Xk = Xq + (size_t)B_ * S_ * H_;
  short* Xv = Xk + (size_t)B_ * S_ * H_;

  dim3 blk(256, 1, 1);

  // 0) all f32->bf16 conversions, one launch
  cvt6<<<dim3(2048, 4, 1), blk, 0, stream>>>(queries, keys, values, Wq, Wk, Wv,
                                             Xq, Xk, Xv, Wqb, Wkb, Wvb);

  // 1) All projections, one launch: M = 32768, N = H, K = H
  ProjArgs pa{Xq, Xk, Xv, Wqb, Wkb, Wvb, bq, bk, bv, Qb, Kb, Vt};
  proj3<<<dim3(H_ / BN, 32768 / BM, 3), blk, 0, stream>>>(pa);

  // 2) Scores (+scale, +causal mask) -> attn region (triangular + last tile-col)
  scores_k<<<dim3(S_ / BM, S_ / BN, B_), blk, 0, stream>>>(Qb, Kb, attn);

  // 3) Column softmax in place + bf16 copy into ws (overwrites Qb/Kb)
  softmax_col<<<dim3(S_ / 32, B_, 1), blk, 0, stream>>>(attn, attn_b);

  // 4) context = attn_b @ V^T (all bf16, triangular K-loop + last k-tile)
  ctx_k<<<dim3(S_ / BM, H_ / BN, B_), blk, 0, stream>>>(attn_b, Vt, ctx);
}

// Round 7
// 894.093 us; speedup vs baseline: 1.2131x; 1.2131x over previous
//
#include <hip/hip_runtime.h>
#include <hip/hip_bf16.h>
#include <stdint.h>

#define B_ 16
#define S_ 2048
#define H_ 1024
static constexpr float NEG_INF_F = -10000000.0f;
static constexpr float SCALE_F   = 0.03125f;   // 1/sqrt(1024)

#define BM 256
#define BN 256
#define BK 64
#define HALF_BYTES 16384     // 128 rows x 64 cols x 2B
#define OPBUF_BYTES 32768    // one operand, one K-tile (2 halves)

typedef __attribute__((ext_vector_type(4))) float  f32x4;
typedef __attribute__((ext_vector_type(8))) short  bf16x8;
typedef __attribute__((ext_vector_type(4))) short  s16x4;

__device__ __forceinline__ short f2bf(float f) {
  uint32_t u = __float_as_uint(f);
  u = (u + 0x7FFFu + ((u >> 16) & 1u)) >> 16;   // RNE bf16
  return (short)u;
}

__device__ __forceinline__ void gload16(const void* g, void* l) {
  __builtin_amdgcn_global_load_lds(
      (const __attribute__((address_space(1))) unsigned int*)g,
      (__attribute__((address_space(3))) unsigned int*)l, 16, 0, 0);
}

// Swizzled LDS fragment read: operand buffer = two 16KB halves of [128][64] bf16.
// XOR-swizzle (T2): byte ^= (row&7)<<4 — same involution as the staging source.
__device__ __forceinline__ bf16x8 lds_frag(const char* buf, int r, int k) {
  int byte = ((r >> 7) << 14) + ((r & 127) << 7) + (k << 1);
  byte ^= (r & 7) << 4;
  return *(const bf16x8*)(buf + byte);
}

// Stage one 128x64 half-tile: linear LDS dest (gload_lds requirement),
// inverse-swizzled per-lane global source (rule #21). 512 threads x 2 loads.
__device__ __forceinline__ void stage_half(const short* __restrict__ rows0,
                                           int ld, int kt, char* dst) {
  const int t = threadIdx.x, w = t >> 6, l = t & 63;
  #pragma unroll
  for (int j = 0; j < 2; ++j) {
    const int idx16 = j * 512 + w * 64 + l;       // 16B-granule index
    const int r  = idx16 >> 3;                    // row 0..127
    const int cs = ((l & 7) << 4) ^ ((r & 7) << 4);
    gload16(rows0 + (size_t)r * ld + kt + (cs >> 1),
            dst + (size_t)(j * 512 + w * 64) * 16);
  }
}

// 256x256xK bf16 GEMM core, 8 waves (2Mx4N), BK=64, double-buffered 128KB LDS.
// 2-deep schedule: all 8 loads of tile i+1 issued at tile i start (the only
// point where buffer c^1 is provably free); 4 MFMA phases on tile i; one
// vmcnt(0)+barrier at tile end. Whole tile resident before phase 0 (the R6
// race fix: every wave reads both A/B halves at phase 0).
// MODE 0: +bias, out bf16 row-major   MODE 1: +bias, out bf16 transposed (V^T)
// MODE 2: out f32 = acc*scale + causal mask    MODE 3: out f32 (context, triangular)
template<int MODE>
__device__ __forceinline__ void gemm_core256(
    const short* __restrict__ A, const short* __restrict__ Bm,
    const float* __restrict__ bias, void* __restrict__ Cp,
    int K, int lda, int ldb, int ldc, int z, long long strC,
    int row0, int col0, int bx, char* lds) {
  char* ldsA = lds;                       // [2][OPBUF]
  char* ldsB = lds + 2 * OPBUF_BYTES;
  const int lane = threadIdx.x & 63;
  const int wid  = threadIdx.x >> 6;
  const int wm = wid >> 2;                // 0..1  (rows wm*128..+127)
  const int wn = wid & 3;                 // 0..3  (cols wn*64..+63)
  const int lr = lane & 15;
  const int lk = (lane >> 4) << 3;

  int kmain = K;
  if constexpr (MODE == 3) { int km = (bx + 1) * BM; kmain = km < K ? km : K; }
  const int ntm = kmain / BK;
  const int nt  = ntm + ((MODE == 3 && kmain < K) ? 1 : 0);  // + last-BK tile (col 2047)

  f32x4 acc[8][4] = {};

  const short* Arows0 = A + (size_t)row0 * lda;
  const short* Arows1 = Arows0 + (size_t)128 * lda;
  const short* Brows0 = Bm + (size_t)col0 * ldb;
  const short* Brows1 = Brows0 + (size_t)128 * ldb;

  auto stage_tile = [&](int buf, int kt) {          // 8 gload16 per thread
    stage_half(Brows0, ldb, kt, ldsB + buf * OPBUF_BYTES);
    stage_half(Brows1, ldb, kt, ldsB + buf * OPBUF_BYTES + HALF_BYTES);
    stage_half(Arows0, lda, kt, ldsA + buf * OPBUF_BYTES);
    stage_half(Arows1, lda, kt, ldsA + buf * OPBUF_BYTES + HALF_BYTES);
  };

  // prologue: tile 0 fully resident before phase 0
  stage_tile(0, 0);
  asm volatile("s_waitcnt vmcnt(0)" ::: "memory");
  __builtin_amdgcn_s_barrier();

  for (int i = 0; i < nt; ++i) {
    const int c = i & 1;
    const char* bA = ldsA + c * OPBUF_BYTES;
    const char* bB = ldsB + c * OPBUF_BYTES;
    if (i + 1 < nt) {                     // prefetch tile i+1 into c^1 (free now)
      const int ktn = (i + 1 < ntm) ? (i + 1) * BK : K - BK;
      stage_tile(c ^ 1, ktn);
    }

    bf16x8 bfr[4][2];
    #pragma unroll
    for (int q = 0; q < 4; ++q) {         // phase q: C-quadrant rows q*32..+31
      if (q == 0) {
        #pragma unroll
        for (int nf = 0; nf < 4; ++nf)
          #pragma unroll
          for (int ks = 0; ks < 2; ++ks)
            bfr[nf][ks] = lds_frag(bB, wn * 64 + nf * 16 + lr, ks * 32 + lk);
      }
      bf16x8 af[2][2];
      #pragma unroll
      for (int fm = 0; fm < 2; ++fm)
        #pragma unroll
        for (int ks = 0; ks < 2; ++ks)
          af[fm][ks] = lds_frag(bA, wm * 128 + q * 32 + fm * 16 + lr, ks * 32 + lk);
      asm volatile("s_waitcnt lgkmcnt(0)" ::: "memory");
      __builtin_amdgcn_sched_barrier(0);  // rule #18: pin MFMA after the wait
      __builtin_amdgcn_s_setprio(1);
      #pragma unroll
      for (int fm = 0; fm < 2; ++fm)
        #pragma unroll
        for (int nf = 0; nf < 4; ++nf)
          #pragma unroll
          for (int ks = 0; ks < 2; ++ks)
            acc[q * 2 + fm][nf] = __builtin_amdgcn_mfma_f32_16x16x32_bf16(
                af[fm][ks], bfr[nf][ks], acc[q * 2 + fm][nf], 0, 0, 0);
      __builtin_amdgcn_s_setprio(0);
      if (q < 3) __builtin_amdgcn_s_barrier();   // lockstep between phases
    }
    // tile end: tile i+1's 8 loads are the only outstanding VMEM -> exact drain;
    // barrier also protects buffer c from next iteration's prefetch overwrite.
    asm volatile("s_waitcnt vmcnt(0)" ::: "memory");
    __builtin_amdgcn_s_barrier();
  }

  // C/D layout per 16x16 frag: col = lane&15, row = (lane>>4)*4 + reg
  #pragma unroll
  for (int mf = 0; mf < 8; ++mf) {
    #pragma unroll
    for (int nf = 0; nf < 4; ++nf) {
      const int mb = row0 + wm * 128 + mf * 16 + ((lane >> 4) << 2);
      const int n  = col0 + wn * 64 + nf * 16 + lr;
      f32x4 a = acc[mf][nf];
      if constexpr (MODE == 0) {
        short* out = (short*)Cp;
        const float bv = bias[n];
        #pragma unroll
        for (int r = 0; r < 4; ++r)
          out[(size_t)(mb + r) * ldc + n] = f2bf(a[r] + bv);
      } else if constexpr (MODE == 1) {
        const float bv = bias[n];
        const int bb = mb >> 11;           // batch (S_=2048)
        const int ss = mb & (S_ - 1);
        s16x4 pk;
        #pragma unroll
        for (int r = 0; r < 4; ++r) pk[r] = f2bf(a[r] + bv);
        *(s16x4*)((short*)Cp + ((size_t)bb * H_ + n) * S_ + ss) = pk;
      } else if constexpr (MODE == 2) {
        float* out = (float*)Cp + (size_t)z * strC;
        #pragma unroll
        for (int r = 0; r < 4; ++r) {
          const int m = mb + r;
          out[(size_t)m * ldc + n] = a[r] * SCALE_F + (n >= m ? NEG_INF_F : 0.0f);
        }
      } else {
        float* out = (float*)Cp + (size_t)z * strC;
        #pragma unroll
        for (int r = 0; r < 4; ++r)
          out[(size_t)(mb + r) * ldc + n] = a[r];
      }
    }
  }
}

struct ProjArgs {
  const short *xq, *xk, *xv, *wq, *wk, *wv;
  const float *bq, *bk, *bv;
  short *oq, *ok, *ov;
};

// All three projections; grid (4, 128, 3), z selects Q/K/V. 512 threads.
__launch_bounds__(512, 1)
__global__ void proj3(ProjArgs p) {
  __shared__ char lds[4 * OPBUF_BYTES];
  const int z = blockIdx.z;
  const int row0 = blockIdx.y * BM;
  const int col0 = blockIdx.x * BN;
  if (z == 0)
    gemm_core256<0>(p.xq, p.wq, p.bq, p.oq, H_, H_, H_, H_, 0, 0LL, row0, col0, blockIdx.x, lds);
  else if (z == 1)
    gemm_core256<0>(p.xk, p.wk, p.bk, p.ok, H_, H_, H_, H_, 0, 0LL, row0, col0, blockIdx.x, lds);
  else
    gemm_core256<1>(p.xv, p.wv, p.bv, p.ov, H_, H_, H_, 0, 0, 0LL, row0, col0, blockIdx.x, lds);
}

// Scores (+scale, +causal mask); triangular tile skip except last tile-column.
__launch_bounds__(512, 1)
__global__ void scores_k(const short* __restrict__ Qb, const short* __restrict__ Kb,
                         float* __restrict__ attn) {
  if (blockIdx.y > blockIdx.x && blockIdx.y != gridDim.y - 1) return;
  __shared__ char lds[4 * OPBUF_BYTES];
  const size_t zo = (size_t)blockIdx.z * S_ * H_;
  gemm_core256<2>(Qb + zo, Kb + zo, nullptr, attn, H_, H_, H_, S_, blockIdx.z,
                  (long long)S_ * S_, blockIdx.x * BM, blockIdx.y * BN, blockIdx.x, lds);
}

// Context = attn_b @ V^T; triangular K-loop (+ last BK tile for column 2047).
__launch_bounds__(512, 1)
__global__ void ctx_k(const short* __restrict__ attn_b, const short* __restrict__ Vt,
                      float* __restrict__ ctx) {
  __shared__ char lds[4 * OPBUF_BYTES];
  gemm_core256<3>(attn_b + (size_t)blockIdx.z * S_ * S_, Vt + (size_t)blockIdx.z * H_ * S_,
                  nullptr, ctx, S_, S_, S_, H_, blockIdx.z, (long long)S_ * H_,
                  blockIdx.x * BM, blockIdx.y * BN, blockIdx.x, lds);
}

// All six f32->bf16 conversions in one launch. grid (2048, 4).
__launch_bounds__(256)
__global__ void cvt6(const float* __restrict__ q, const float* __restrict__ k,
                     const float* __restrict__ v, const float* __restrict__ wq,
                     const float* __restrict__ wk, const float* __restrict__ wv,
                     short* __restrict__ xq, short* __restrict__ xk,
                     short* __restrict__ xv, short* __restrict__ wqb,
                     short* __restrict__ wkb, short* __restrict__ wvb) {
  const int y = blockIdx.y;
  const int stride = gridDim.x * 256;
  if (y < 3) {
    const float* s = (y == 0) ? q : (y == 1) ? k : v;
    short* d       = (y == 0) ? xq : (y == 1) ? xk : xv;
    const int n4 = (B_ * S_ * H_) / 4;
    for (int i = blockIdx.x * 256 + threadIdx.x; i < n4; i += stride) {
      f32x4 x = ((const f32x4*)s)[i];
      s16x4 o;
      #pragma unroll
      for (int j = 0; j < 4; ++j) o[j] = f2bf(x[j]);
      ((s16x4*)d)[i] = o;
    }
  } else {
    const int w4 = (H_ * H_) / 4;          // 2^18
    for (int i = blockIdx.x * 256 + threadIdx.x; i < 3 * w4; i += stride) {
      const int wsel = i >> 18;
      const int j = i & (w4 - 1);
      const float* s = (wsel == 0) ? wq : (wsel == 1) ? wk : wv;
      short* d       = (wsel == 0) ? wqb : (wsel == 1) ? wkb : wvb;
      f32x4 x = ((const f32x4*)s)[j];
      s16x4 o;
      #pragma unroll
      for (int jj = 0; jj < 4; ++jj) o[jj] = f2bf(x[jj]);
      ((s16x4*)d)[j] = o;
    }
  }
}

// Column softmax (over q axis) in place on attn (B,S,S) f32; also writes a bf16
// copy for the context GEMM. Rows q<=k are exact zeros (written, not computed).
__launch_bounds__(256)
__global__ void softmax_col(float* __restrict__ attn, short* __restrict__ attn_b) {
  const int b  = blockIdx.y;
  const int t  = threadIdx.x;
  const int cg = t & 7;
  const int qo = t >> 3;                  // 0..31
  const int k0 = blockIdx.x * 32 + cg * 4;
  float* base = attn + (size_t)b * S_ * S_;
  short* bb   = attn_b + (size_t)b * S_ * S_;
  const bool full = (k0 == S_ - 4);       // group holding the all-masked col S-1

  int qstart;
  if (full) qstart = qo;
  else { const int s0 = k0 + 1; qstart = s0 + ((qo - s0) & 31); }

  f32x4 m4, s4;
  #pragma unroll
  for (int i = 0; i < 4; ++i) { m4[i] = -3.0e38f; s4[i] = 0.0f; }

  for (int q = qstart; q < S_; q += 32) {
    f32x4 x = *(const f32x4*)&base[(size_t)q * S_ + k0];
    #pragma unroll
    for (int i = 0; i < 4; ++i) {
      float mn = fmaxf(m4[i], x[i]);
      s4[i] = s4[i] * __expf(m4[i] - mn) + __expf(x[i] - mn);
      m4[i] = mn;
    }
  }

  __shared__ f32x4 smx[32][8];
  __shared__ f32x4 ssx[32][8];
  smx[qo][cg] = m4;
  ssx[qo][cg] = s4;
  __syncthreads();

  f32x4 M4, Sm;
  #pragma unroll
  for (int i = 0; i < 4; ++i) { M4[i] = -3.0e38f; Sm[i] = 0.0f; }
  for (int j = 0; j < 32; ++j) {
    f32x4 mm = smx[j][cg];
    #pragma unroll
    for (int i = 0; i < 4; ++i) M4[i] = fmaxf(M4[i], mm[i]);
  }
  for (int j = 0; j < 32; ++j) {
    f32x4 mm = smx[j][cg], ssv = ssx[j][cg];
    #pragma unroll
    for (int i = 0; i < 4; ++i) Sm[i] += ssv[i] * __expf(mm[i] - M4[i]);
  }
  f32x4 inv;
  #pragma unroll
  for (int i = 0; i < 4; ++i) inv[i] = 1.0f / Sm[i];

  for (int q = qo; q < S_; q += 32) {
    const size_t off = (size_t)q * S_ + k0;
    if (full || q > k0) {
      f32x4 x = *(const f32x4*)&base[off];
      f32x4 r;
      s16x4 rb;
      #pragma unroll
      for (int i = 0; i < 4; ++i) { r[i] = __expf(x[i] - M4[i]) * inv[i]; rb[i] = f2bf(r[i]); }
      *(f32x4*)&base[off] = r;
      *(s16x4*)&bb[off]   = rb;
    } else {
      f32x4 zr;
      s16x4 zb;
      #pragma unroll
      for (int i = 0; i < 4; ++i) { zr[i] = 0.0f; zb[i] = 0; }
      *(f32x4*)&base[off] = zr;
      *(s16x4*)&bb[off]   = zb;
    }
  }
}

extern "C" void kernel_launch(void* const* d_in, const int* in_sizes, int n_in,
                              void* d_out, int out_size, void* d_ws, size_t ws_size,
                              hipStream_t stream) {
  const float* queries = (const float*)d_in[0];
  const float* keys    = (const float*)d_in[1];
  const float* values  = (const float*)d_in[2];
  const float* Wq = (const float*)d_in[3];
  const float* bq = (const float*)d_in[4];
  const float* Wk = (const float*)d_in[5];
  const float* bk = (const float*)d_in[6];
  const float* Wv = (const float*)d_in[7];
  const float* bv = (const float*)d_in[8];

  float* ctx  = (float*)d_out;                       // (B,S,H) f32
  float* attn = ctx + (size_t)B_ * S_ * H_;          // (B,S,S) f32

  short* Qb = (short*)d_ws;                          // (B,S,H) bf16
  short* Kb = Qb + (size_t)B_ * S_ * H_;
  short* Vt = Kb + (size_t)B_ * S_ * H_;             // (B,H,S) bf16
  short* attn_b = Qb;                                // (B,S,S) bf16 reuses Qb+Kb

  // bf16 input/weight scratch inside d_out regions written later:
  short* Wqb = (short*)ctx;                          // 3x (H,H) bf16 in ctx region
  short* Wkb = Wqb + (size_t)H_ * H_;
  short* Wvb = Wkb + (size_t)H_ * H_;
  short* Xq = (short*)attn;                          // 3x (B,S,H) bf16 in attn region
  short* Xk = Xq + (size_t)B_ * S_ * H_;
  short* Xv = Xk + (size_t)B_ * S_ * H_;

  // 0) all f32->bf16 conversions, one launch
  cvt6<<<dim3(2048, 4, 1), dim3(256, 1, 1), 0, stream>>>(queries, keys, values,
                                                         Wq, Wk, Wv,
                                                         Xq, Xk, Xv, Wqb, Wkb, Wvb);

  // 1) All projections, one launch: M = 32768, N = H, K = H
  ProjArgs pa{Xq, Xk, Xv, Wqb, Wkb, Wvb, bq, bk, bv, Qb, Kb, Vt};
  proj3<<<dim3(H_ / BN, 32768 / BM, 3), dim3(512, 1, 1), 0, stream>>>(pa);

  // 2) Scores (+scale, +causal mask) -> attn region (triangular + last tile-col)
  scores_k<<<dim3(S_ / BM, S_ / BN, B_), dim3(512, 1, 1), 0, stream>>>(Qb, Kb, attn);

  // 3) Column softmax in place + bf16 copy into ws (overwrites Qb/Kb)
  softmax_col<<<dim3(S_ / 32, B_, 1), dim3(256, 1, 1), 0, stream>>>(attn, attn_b);

  // 4) context = attn_b @ V^T (all bf16, triangular K-loop + last BK tile)
  ctx_k<<<dim3(S_ / BM, H_ / BN, B_), dim3(512, 1, 1), 0, stream>>>(attn_b, Vt, ctx);
}

// Round 8
// 828.566 us; speedup vs baseline: 1.3091x; 1.0791x over previous
//
#include <hip/hip_runtime.h>
#include <hip/hip_bf16.h>
#include <stdint.h>

#define B_ 16
#define S_ 2048
#define H_ 1024
static constexpr float NEG_INF_F = -10000000.0f;
static constexpr float SCALE_F   = 0.03125f;   // 1/sqrt(1024)

#define BM 256
#define BN 256
#define BK 64
#define HALF_BYTES 16384     // 128 rows x 64 cols x 2B
#define OPBUF_BYTES 32768    // one operand, one K-tile (2 halves)

typedef __attribute__((ext_vector_type(4))) float  f32x4;
typedef __attribute__((ext_vector_type(8))) short  bf16x8;
typedef __attribute__((ext_vector_type(4))) short  s16x4;

__device__ __forceinline__ short f2bf(float f) {
  uint32_t u = __float_as_uint(f);
  u = (u + 0x7FFFu + ((u >> 16) & 1u)) >> 16;   // RNE bf16
  return (short)u;
}

__device__ __forceinline__ void gload16(const void* g, void* l) {
  __builtin_amdgcn_global_load_lds(
      (const __attribute__((address_space(1))) unsigned int*)g,
      (__attribute__((address_space(3))) unsigned int*)l, 16, 0, 0);
}

// Swizzled LDS fragment read: operand buffer = two 16KB halves of [128][64] bf16.
// XOR-swizzle (T2): byte ^= (row&7)<<4 — same involution as the staging source.
__device__ __forceinline__ bf16x8 lds_frag(const char* buf, int r, int k) {
  int byte = ((r >> 7) << 14) + ((r & 127) << 7) + (k << 1);
  byte ^= (r & 7) << 4;
  return *(const bf16x8*)(buf + byte);
}

// Stage one 128x64 half-tile: linear LDS dest (gload_lds requirement),
// inverse-swizzled per-lane global source (rule #21). 512 threads x 2 loads.
__device__ __forceinline__ void stage_half(const short* __restrict__ rows0,
                                           int ld, int kt, char* dst) {
  const int t = threadIdx.x, w = t >> 6, l = t & 63;
  #pragma unroll
  for (int j = 0; j < 2; ++j) {
    const int idx16 = j * 512 + w * 64 + l;       // 16B-granule index
    const int r  = idx16 >> 3;                    // row 0..127
    const int cs = ((l & 7) << 4) ^ ((r & 7) << 4);
    gload16(rows0 + (size_t)r * ld + kt + (cs >> 1),
            dst + (size_t)(j * 512 + w * 64) * 16);
  }
}

// 256x256xK bf16 GEMM core, 8 waves (2Mx4N), BK=64, double-buffered 128KB LDS.
// 2-deep schedule: all 8 loads of tile i+1 issued at tile i start; 4 MFMA
// phases on tile i; vmcnt(0)+barrier at tile end (proven race-free, R7).
// MODE 0: +bias, out bf16 row-major   MODE 1: +bias, out bf16 transposed (V^T)
// MODE 2: out f32 = acc*scale + causal mask, + column (max,sumexp) partials
// MODE 3: out f32 (context, triangular K-loop + last BK tile)
template<int MODE>
__device__ __forceinline__ void gemm_core256(
    const short* __restrict__ A, const short* __restrict__ Bm,
    const float* __restrict__ bias, void* __restrict__ Cp,
    int K, int lda, int ldb, int ldc, int z, long long strC,
    int row0, int col0, int bx, char* lds, float2* __restrict__ partials) {
  char* ldsA = lds;                       // [2][OPBUF]
  char* ldsB = lds + 2 * OPBUF_BYTES;
  const int lane = threadIdx.x & 63;
  const int wid  = threadIdx.x >> 6;
  const int wm = wid >> 2;                // 0..1  (rows wm*128..+127)
  const int wn = wid & 3;                 // 0..3  (cols wn*64..+63)
  const int lr = lane & 15;
  const int lk = (lane >> 4) << 3;

  int kmain = K;
  if constexpr (MODE == 3) { int km = (bx + 1) * BM; kmain = km < K ? km : K; }
  const int ntm = kmain / BK;
  const int nt  = ntm + ((MODE == 3 && kmain < K) ? 1 : 0);  // + last-BK tile (col 2047)

  f32x4 acc[8][4] = {};

  const short* Arows0 = A + (size_t)row0 * lda;
  const short* Arows1 = Arows0 + (size_t)128 * lda;
  const short* Brows0 = Bm + (size_t)col0 * ldb;
  const short* Brows1 = Brows0 + (size_t)128 * ldb;

  auto stage_tile = [&](int buf, int kt) {          // 8 gload16 per thread
    stage_half(Brows0, ldb, kt, ldsB + buf * OPBUF_BYTES);
    stage_half(Brows1, ldb, kt, ldsB + buf * OPBUF_BYTES + HALF_BYTES);
    stage_half(Arows0, lda, kt, ldsA + buf * OPBUF_BYTES);
    stage_half(Arows1, lda, kt, ldsA + buf * OPBUF_BYTES + HALF_BYTES);
  };

  // prologue: tile 0 fully resident before phase 0
  stage_tile(0, 0);
  asm volatile("s_waitcnt vmcnt(0)" ::: "memory");
  __builtin_amdgcn_s_barrier();

  for (int i = 0; i < nt; ++i) {
    const int c = i & 1;
    const char* bA = ldsA + c * OPBUF_BYTES;
    const char* bB = ldsB + c * OPBUF_BYTES;
    if (i + 1 < nt) {                     // prefetch tile i+1 into c^1 (free now)
      const int ktn = (i + 1 < ntm) ? (i + 1) * BK : K - BK;
      stage_tile(c ^ 1, ktn);
    }

    bf16x8 bfr[4][2];
    #pragma unroll
    for (int q = 0; q < 4; ++q) {         // phase q: C-quadrant rows q*32..+31
      if (q == 0) {
        #pragma unroll
        for (int nf = 0; nf < 4; ++nf)
          #pragma unroll
          for (int ks = 0; ks < 2; ++ks)
            bfr[nf][ks] = lds_frag(bB, wn * 64 + nf * 16 + lr, ks * 32 + lk);
      }
      bf16x8 af[2][2];
      #pragma unroll
      for (int fm = 0; fm < 2; ++fm)
        #pragma unroll
        for (int ks = 0; ks < 2; ++ks)
          af[fm][ks] = lds_frag(bA, wm * 128 + q * 32 + fm * 16 + lr, ks * 32 + lk);
      asm volatile("s_waitcnt lgkmcnt(0)" ::: "memory");
      __builtin_amdgcn_sched_barrier(0);  // rule #18: pin MFMA after the wait
      __builtin_amdgcn_s_setprio(1);
      #pragma unroll
      for (int fm = 0; fm < 2; ++fm)
        #pragma unroll
        for (int nf = 0; nf < 4; ++nf)
          #pragma unroll
          for (int ks = 0; ks < 2; ++ks)
            acc[q * 2 + fm][nf] = __builtin_amdgcn_mfma_f32_16x16x32_bf16(
                af[fm][ks], bfr[nf][ks], acc[q * 2 + fm][nf], 0, 0, 0);
      __builtin_amdgcn_s_setprio(0);
      if (q < 3) __builtin_amdgcn_s_barrier();   // lockstep between phases
    }
    asm volatile("s_waitcnt vmcnt(0)" ::: "memory");
    __builtin_amdgcn_s_barrier();
  }

  float pm[4] = {-3.0e38f, -3.0e38f, -3.0e38f, -3.0e38f};

  // C/D layout per 16x16 frag: col = lane&15, row = (lane>>4)*4 + reg
  #pragma unroll
  for (int mf = 0; mf < 8; ++mf) {
    #pragma unroll
    for (int nf = 0; nf < 4; ++nf) {
      const int mb = row0 + wm * 128 + mf * 16 + ((lane >> 4) << 2);
      const int n  = col0 + wn * 64 + nf * 16 + lr;
      f32x4 a = acc[mf][nf];
      if constexpr (MODE == 0) {
        short* out = (short*)Cp;
        const float bv = bias[n];
        #pragma unroll
        for (int r = 0; r < 4; ++r)
          out[(size_t)(mb + r) * ldc + n] = f2bf(a[r] + bv);
      } else if constexpr (MODE == 1) {
        const float bv = bias[n];
        const int bb = mb >> 11;           // batch (S_=2048)
        const int ss = mb & (S_ - 1);
        s16x4 pk;
        #pragma unroll
        for (int r = 0; r < 4; ++r) pk[r] = f2bf(a[r] + bv);
        *(s16x4*)((short*)Cp + ((size_t)bb * H_ + n) * S_ + ss) = pk;
      } else if constexpr (MODE == 2) {
        float* out = (float*)Cp + (size_t)z * strC;
        #pragma unroll
        for (int r = 0; r < 4; ++r) {
          const int mrow = mb + r;
          float v = a[r] * SCALE_F + (n >= mrow ? NEG_INF_F : 0.0f);
          out[(size_t)mrow * ldc + n] = v;
          pm[nf] = fmaxf(pm[nf], v);
        }
      } else {
        float* out = (float*)Cp + (size_t)z * strC;
        #pragma unroll
        for (int r = 0; r < 4; ++r)
          out[(size_t)(mb + r) * ldc + n] = a[r];
      }
    }
  }

  if constexpr (MODE == 2) {
    // Column softmax partials over this tile's 256 rows (flash-style).
    float ps[4] = {0.0f, 0.0f, 0.0f, 0.0f};
    #pragma unroll
    for (int mf = 0; mf < 8; ++mf)
      #pragma unroll
      for (int nf = 0; nf < 4; ++nf) {
        const int mb = row0 + wm * 128 + mf * 16 + ((lane >> 4) << 2);
        const int n  = col0 + wn * 64 + nf * 16 + lr;
        f32x4 a = acc[mf][nf];
        #pragma unroll
        for (int r = 0; r < 4; ++r) {
          float v = a[r] * SCALE_F + (n >= mb + r ? NEG_INF_F : 0.0f);
          ps[nf] += __expf(v - pm[nf]);   // masked: exp(-1e7-ish) == 0 exactly
        }
      }
    float* smx = (float*)lds;             // reuse LDS (dead after K-loop)
    float* sse = smx + 512;
    #pragma unroll
    for (int nf = 0; nf < 4; ++nf) {
      float m = pm[nf], s = ps[nf];
      #pragma unroll
      for (int d = 16; d < 64; d <<= 1) { // combine lanes lr, lr+16, +32, +48
        float om = __shfl_xor(m, d);
        float os = __shfl_xor(s, d);
        float nm = fmaxf(m, om);
        s = s * __expf(m - nm) + os * __expf(om - nm);
        m = nm;
      }
      if ((lane >> 4) == 0) {
        smx[wm * 256 + wn * 64 + nf * 16 + lr] = m;
        sse[wm * 256 + wn * 64 + nf * 16 + lr] = s;
      }
    }
    __syncthreads();
    if (threadIdx.x < 256) {
      const int col = threadIdx.x;
      float m0 = smx[col], m1 = smx[256 + col];
      float s0 = sse[col], s1 = sse[256 + col];
      float mm = fmaxf(m0, m1);
      float ss = s0 * __expf(m0 - mm) + s1 * __expf(m1 - mm);
      float2 pv; pv.x = mm; pv.y = ss;
      partials[((size_t)z * 8 + (row0 >> 8)) * S_ + col0 + col] = pv;
    }
  }
}

struct ProjArgs {
  const short *xq, *xk, *xv, *wq, *wk, *wv;
  const float *bq, *bk, *bv;
  short *oq, *ok, *ov;
};

// All three projections; grid (4, 128, 3) = 1536 blocks, XCD-chunked swizzle.
__launch_bounds__(512, 1)
__global__ void proj3(ProjArgs p) {
  __shared__ char lds[4 * OPBUF_BYTES];
  const int bid = blockIdx.x + (blockIdx.y << 2) + (blockIdx.z << 9);
  const int s = (bid & 7) * 192 + (bid >> 3);       // 1536/8 = 192, bijective
  const int z = s >> 9;
  const int y = (s & 511) >> 2;
  const int x = s & 3;
  const int row0 = y * BM;
  const int col0 = x * BN;
  if (z == 0)
    gemm_core256<0>(p.xq, p.wq, p.bq, p.oq, H_, H_, H_, H_, 0, 0LL, row0, col0, x, lds, nullptr);
  else if (z == 1)
    gemm_core256<0>(p.xk, p.wk, p.bk, p.ok, H_, H_, H_, H_, 0, 0LL, row0, col0, x, lds, nullptr);
  else
    gemm_core256<1>(p.xv, p.wv, p.bv, p.ov, H_, H_, H_, 0, 0, 0LL, row0, col0, x, lds, nullptr);
}

// Scores (+scale, +causal mask, +column partials); triangular tile skip except
// last tile-column. grid (8,8,16) = 1024 blocks, XCD-chunked swizzle.
__launch_bounds__(512, 1)
__global__ void scores_k(const short* __restrict__ Qb, const short* __restrict__ Kb,
                         float* __restrict__ attn, float2* __restrict__ partials) {
  const int bid = blockIdx.x + (blockIdx.y << 3) + (blockIdx.z << 6);
  const int s = (bid & 7) * 128 + (bid >> 3);       // 1024/8 = 128, bijective
  const int bz = s >> 6;
  const int by = (s >> 3) & 7;
  const int bx = s & 7;
  if (by > bx && by != 7) return;
  __shared__ char lds[4 * OPBUF_BYTES];
  const size_t zo = (size_t)bz * S_ * H_;
  gemm_core256<2>(Qb + zo, Kb + zo, nullptr, attn, H_, H_, H_, S_, bz,
                  (long long)S_ * S_, bx * BM, by * BN, bx, lds, partials);
}

// Context = attn_b @ V^T; triangular K-loop (+ last BK tile for column 2047).
// grid (8,4,16) = 512 blocks, XCD-chunked swizzle.
__launch_bounds__(512, 1)
__global__ void ctx_k(const short* __restrict__ attn_b, const short* __restrict__ Vt,
                      float* __restrict__ ctx) {
  const int bid = blockIdx.x + (blockIdx.y << 3) + (blockIdx.z << 5);
  const int s = (bid & 7) * 64 + (bid >> 3);        // 512/8 = 64, bijective
  const int bz = s >> 5;
  const int by = (s >> 3) & 3;
  const int bx = s & 7;
  __shared__ char lds[4 * OPBUF_BYTES];
  gemm_core256<3>(attn_b + (size_t)bz * S_ * S_, Vt + (size_t)bz * H_ * S_,
                  nullptr, ctx, S_, S_, S_, H_, bz, (long long)S_ * H_,
                  bx * BM, by * BN, bx, lds, nullptr);
}

// All six f32->bf16 conversions in one launch. grid (2048, 4).
__launch_bounds__(256)
__global__ void cvt6(const float* __restrict__ q, const float* __restrict__ k,
                     const float* __restrict__ v, const float* __restrict__ wq,
                     const float* __restrict__ wk, const float* __restrict__ wv,
                     short* __restrict__ xq, short* __restrict__ xk,
                     short* __restrict__ xv, short* __restrict__ wqb,
                     short* __restrict__ wkb, short* __restrict__ wvb) {
  const int y = blockIdx.y;
  const int stride = gridDim.x * 256;
  if (y < 3) {
    const float* s = (y == 0) ? q : (y == 1) ? k : v;
    short* d       = (y == 0) ? xq : (y == 1) ? xk : xv;
    const int n4 = (B_ * S_ * H_) / 4;
    for (int i = blockIdx.x * 256 + threadIdx.x; i < n4; i += stride) {
      f32x4 x = ((const f32x4*)s)[i];
      s16x4 o;
      #pragma unroll
      for (int j = 0; j < 4; ++j) o[j] = f2bf(x[j]);
      ((s16x4*)d)[i] = o;
    }
  } else {
    const int w4 = (H_ * H_) / 4;          // 2^18
    for (int i = blockIdx.x * 256 + threadIdx.x; i < 3 * w4; i += stride) {
      const int wsel = i >> 18;
      const int j = i & (w4 - 1);
      const float* s = (wsel == 0) ? wq : (wsel == 1) ? wk : wv;
      short* d       = (wsel == 0) ? wqb : (wsel == 1) ? wkb : wvb;
      f32x4 x = ((const f32x4*)s)[j];
      s16x4 o;
      #pragma unroll
      for (int jj = 0; jj < 4; ++jj) o[jj] = f2bf(x[jj]);
      ((s16x4*)d)[j] = o;
    }
  }
}

// Column softmax normalize pass: combine per-tile partials (no raw re-read),
// then a single read+write pass producing f32 attn + bf16 copy.
__launch_bounds__(256)
__global__ void softmax_col(float* __restrict__ attn, short* __restrict__ attn_b,
                            const float2* __restrict__ partials) {
  const int b  = blockIdx.y;
  const int t  = threadIdx.x;
  const int cg = t & 7;
  const int qo = t >> 3;                  // 0..31
  const int k0 = blockIdx.x * 32 + cg * 4;
  float* base = attn + (size_t)b * S_ * S_;
  short* bb   = attn_b + (size_t)b * S_ * S_;
  const bool full = (k0 == S_ - 4);       // group holding the all-masked col S-1

  __shared__ f32x4 bM[8], bI[8];
  if (qo == 0) {
    const int by = k0 >> 8;
    const int bxlo = (by == 7) ? 0 : by;  // tiles scores_k actually computed
    f32x4 M4, Sm;
    #pragma unroll
    for (int i = 0; i < 4; ++i) { M4[i] = -3.0e38f; Sm[i] = 0.0f; }
    for (int bx = bxlo; bx < 8; ++bx) {
      const float2* p = partials + ((size_t)b * 8 + bx) * S_ + k0;
      #pragma unroll
      for (int i = 0; i < 4; ++i) {
        float2 pv = p[i];
        float nm = fmaxf(M4[i], pv.x);
        Sm[i] = Sm[i] * __expf(M4[i] - nm) + pv.y * __expf(pv.x - nm);
        M4[i] = nm;
      }
    }
    f32x4 inv;
    #pragma unroll
    for (int i = 0; i < 4; ++i) inv[i] = 1.0f / Sm[i];
    bM[cg] = M4;
    bI[cg] = inv;
  }
  __syncthreads();
  const f32x4 M4  = bM[cg];
  const f32x4 inv = bI[cg];

  for (int q = qo; q < S_; q += 32) {
    const size_t off = (size_t)q * S_ + k0;
    if (full || q > k0) {
      f32x4 x = *(const f32x4*)&base[off];
      f32x4 r;
      s16x4 rb;
      #pragma unroll
      for (int i = 0; i < 4; ++i) { r[i] = __expf(x[i] - M4[i]) * inv[i]; rb[i] = f2bf(r[i]); }
      *(f32x4*)&base[off] = r;
      *(s16x4*)&bb[off]   = rb;
    } else {
      f32x4 zr;
      s16x4 zb;
      #pragma unroll
      for (int i = 0; i < 4; ++i) { zr[i] = 0.0f; zb[i] = 0; }
      *(f32x4*)&base[off] = zr;
      *(s16x4*)&bb[off]   = zb;
    }
  }
}

extern "C" void kernel_launch(void* const* d_in, const int* in_sizes, int n_in,
                              void* d_out, int out_size, void* d_ws, size_t ws_size,
                              hipStream_t stream) {
  const float* queries = (const float*)d_in[0];
  const float* keys    = (const float*)d_in[1];
  const float* values  = (const float*)d_in[2];
  const float* Wq = (const float*)d_in[3];
  const float* bq = (const float*)d_in[4];
  const float* Wk = (const float*)d_in[5];
  const float* bk = (const float*)d_in[6];
  const float* Wv = (const float*)d_in[7];
  const float* bv = (const float*)d_in[8];

  float* ctx  = (float*)d_out;                       // (B,S,H) f32
  float* attn = ctx + (size_t)B_ * S_ * H_;          // (B,S,S) f32

  short* Qb = (short*)d_ws;                          // (B,S,H) bf16
  short* Kb = Qb + (size_t)B_ * S_ * H_;
  short* Vt = Kb + (size_t)B_ * S_ * H_;             // (B,H,S) bf16
  short* attn_b = Qb;                                // (B,S,S) bf16 == Qb+Kb exactly

  // bf16 weight scratch + softmax partials inside ctx region (written last):
  short* Wqb = (short*)ctx;                          // 3x (H,H) bf16 = 6 MB
  short* Wkb = Wqb + (size_t)H_ * H_;
  short* Wvb = Wkb + (size_t)H_ * H_;
  float2* partials = (float2*)(Wvb + (size_t)H_ * H_);  // (B,8,S) float2 = 2 MB
  short* Xq = (short*)attn;                          // 3x (B,S,H) bf16 in attn region
  short* Xk = Xq + (size_t)B_ * S_ * H_;
  short* Xv = Xk + (size_t)B_ * S_ * H_;

  // 0) all f32->bf16 conversions, one launch
  cvt6<<<dim3(2048, 4, 1), dim3(256, 1, 1), 0, stream>>>(queries, keys, values,
                                                         Wq, Wk, Wv,
                                                         Xq, Xk, Xv, Wqb, Wkb, Wvb);

  // 1) All projections, one launch: M = 32768, N = H, K = H
  ProjArgs pa{Xq, Xk, Xv, Wqb, Wkb, Wvb, bq, bk, bv, Qb, Kb, Vt};
  proj3<<<dim3(H_ / BN, 32768 / BM, 3), dim3(512, 1, 1), 0, stream>>>(pa);

  // 2) Scores (+scale, +causal mask, +partials) -> attn region
  scores_k<<<dim3(S_ / BM, S_ / BN, B_), dim3(512, 1, 1), 0, stream>>>(Qb, Kb, attn, partials);

  // 3) Column softmax normalize (partials-based, single pass) + bf16 copy
  softmax_col<<<dim3(S_ / 32, B_, 1), dim3(256, 1, 1), 0, stream>>>(attn, attn_b, partials);

  // 4) context = attn_b @ V^T (all bf16, triangular K-loop + last BK tile)
  ctx_k<<<dim3(S_ / BM, H_ / BN, B_), dim3(512, 1, 1), 0, stream>>>(attn_b, Vt, ctx);
}